// Round 14
// baseline (705.685 us; speedup 1.0000x reference)
//
#include <hip/hip_runtime.h>
#include <hip/hip_fp16.h>
#include <math.h>

typedef _Float16 f16x4 __attribute__((ext_vector_type(4)));
typedef float    f32x4 __attribute__((ext_vector_type(4)));

// ---------------------------------------------------------------------------
// W fp32 [L][k][n] (n=128) -> fp16 transposed Wt [L][n][k]
// ---------------------------------------------------------------------------
template<int K>
__global__ void convert_w_k(const float* __restrict__ W, __half* __restrict__ Wt,
                            int total)
{
    int i = blockIdx.x * 256 + threadIdx.x;
    if (i >= total) return;
    const int nk = 128 * K;
    const int l = i / nk;
    const int rem = i % nk;
    const int n = rem / K;
    const int k = rem % K;
    Wt[i] = __float2half(W[(size_t)l * nk + k * 128 + n]);
}

// ---------------------------------------------------------------------------
// MFMA dense: out[M,128] = A[M,K] @ W(fp16) [+bias] [*rowscale], out fp16.
// IN_HALF: A is fp16 (loaded raw); else fp32 (converted during staging).
// ---------------------------------------------------------------------------
template<int K, bool HAS_BIAS, bool IN_HALF, bool SCALE>
__global__ __launch_bounds__(256) void dense_mfma_k(
    const void* __restrict__ A_, const __half* __restrict__ Wt,
    const float* __restrict__ bias, const float* __restrict__ rowscale,
    __half* __restrict__ out, int M)
{
    constexpr int KP = K + 8;
    __shared__ _Float16 Ah[64 * KP];
    __shared__ _Float16 Wl[128 * KP];

    const int t = threadIdx.x;
    const long row0 = (long)blockIdx.x * 64;

    for (int i = t; i < K * 16; i += 256) {
        const int n = i / (K / 8);
        const int kq = i % (K / 8);
        *(float4*)&Wl[n * KP + kq * 8] = *(const float4*)&Wt[n * K + kq * 8];
    }
    if constexpr (IN_HALF) {
        const __half* A = (const __half*)A_;
        for (int i = t; i < K * 8; i += 256) {
            const int r = i / (K / 8);
            const int kq = i % (K / 8);
            long gr = row0 + r; if (gr > (long)M - 1) gr = (long)M - 1;
            *(float4*)&Ah[r * KP + kq * 8] = *(const float4*)&A[gr * K + kq * 8];
        }
    } else {
        const float* A = (const float*)A_;
        for (int i = t; i < K * 16; i += 256) {
            const int r = i / (K / 4);
            const int kq = i % (K / 4);
            long gr = row0 + r; if (gr > (long)M - 1) gr = (long)M - 1;
            const float4 v = *(const float4*)&A[gr * K + kq * 4];
            f16x4 h4 = { (_Float16)v.x, (_Float16)v.y, (_Float16)v.z, (_Float16)v.w };
            *(f16x4*)&Ah[r * KP + kq * 4] = h4;
        }
    }
    __syncthreads();

    const int wid = t >> 6;
    const int lane = t & 63;
    const int lrow = lane & 15;
    const int lk = (lane >> 4) * 4;

    f32x4 acc[8];
#pragma unroll
    for (int c = 0; c < 8; c++) acc[c] = f32x4{0.f, 0.f, 0.f, 0.f};

#pragma unroll
    for (int kc = 0; kc < K / 16; kc++) {
        const int kbase = kc * 16 + lk;
        const f16x4 a = *(const f16x4*)&Ah[(wid * 16 + lrow) * KP + kbase];
#pragma unroll
        for (int c = 0; c < 8; c++) {
            const f16x4 b = *(const f16x4*)&Wl[(c * 16 + lrow) * KP + kbase];
            acc[c] = __builtin_amdgcn_mfma_f32_16x16x16f16(a, b, acc[c], 0, 0, 0);
        }
    }

    const int orow = wid * 16 + (lane >> 4) * 4;
#pragma unroll
    for (int r = 0; r < 4; r++) {
        const long grow = row0 + orow + r;
        if (grow < M) {
            const float sc = SCALE ? rowscale[grow] : 1.0f;
#pragma unroll
            for (int c = 0; c < 8; c++) {
                float v = acc[c][r];
                if (HAS_BIAS) v += bias[c * 16 + lrow];
                out[grow * 128 + c * 16 + lrow] = __float2half(v * sc);
            }
        }
    }
}

// ---------------------------------------------------------------------------
// Degree count + rank capture
// ---------------------------------------------------------------------------
__global__ void count_edges_k(const int* __restrict__ dst, int* __restrict__ cnt,
                              int* __restrict__ rank, int E)
{
    int e = blockIdx.x * 256 + threadIdx.x;
    if (e < E) rank[e] = atomicAdd(&cnt[dst[e]], 1);
}

// ---------------------------------------------------------------------------
// Block scan (+ dinv computed here)
// ---------------------------------------------------------------------------
__global__ void scan_block_k(const int* __restrict__ cnt, int* __restrict__ offs,
                             int* __restrict__ bsums, float* __restrict__ dinv, int N)
{
    __shared__ int tmp[256];
    int i = blockIdx.x * 256 + threadIdx.x;
    int v = (i < N) ? cnt[i] : 0;
    if (i < N) dinv[i] = rsqrtf((float)v + 1.0f);   // +1 = self loop
    tmp[threadIdx.x] = v;
    __syncthreads();
    for (int off = 1; off < 256; off <<= 1) {
        int add = (threadIdx.x >= off) ? tmp[threadIdx.x - off] : 0;
        __syncthreads();
        tmp[threadIdx.x] += add;
        __syncthreads();
    }
    if (i < N) offs[i] = tmp[threadIdx.x] - v;
    if (threadIdx.x == 255) bsums[blockIdx.x] = tmp[255];
}

__global__ void scan_tops_k(int* __restrict__ bsums, int nb)
{
    __shared__ int tmp[512];
    int t = threadIdx.x;
    int v = (t < nb) ? bsums[t] : 0;
    tmp[t] = v;
    __syncthreads();
    for (int off = 1; off < 512; off <<= 1) {
        int add = (t >= off) ? tmp[t - off] : 0;
        __syncthreads();
        tmp[t] += add;
        __syncthreads();
    }
    if (t < nb) bsums[t] = tmp[t] - v;
}

__global__ void scan_add_k(int* __restrict__ offs, const int* __restrict__ bsums,
                           int N, int E)
{
    int i = blockIdx.x * 256 + threadIdx.x;
    if (i < N) offs[i] += bsums[blockIdx.x];
    if (i == 0) offs[N] = E;
}

// ---------------------------------------------------------------------------
// CSR fill: slot = offs[dst] + rank (atomic-free)
// ---------------------------------------------------------------------------
__global__ void fill_csr_k(const int* __restrict__ src, const int* __restrict__ dst,
                           const int* __restrict__ offs, const int* __restrict__ rank,
                           int* __restrict__ csr, int E)
{
    int e = blockIdx.x * 256 + threadIdx.x;
    if (e >= E) return;
    csr[offs[dst[e]] + rank[e]] = src[e];
}

// ---------------------------------------------------------------------------
// Aggregation v4: half-wave 2-edges/VMEM + packed-fp16 tree accumulation.
// Per 8-edge iter: 4 rows tree-reduced with v_pk_add_f16 (6 ops) then one
// conversion into the fp32 accumulator. csr stream loaded non-temporally.
// ---------------------------------------------------------------------------
template<bool OUT_HALF>
__global__ __launch_bounds__(256) void aggregate_k(
    const __half2* __restrict__ hws2, const int* __restrict__ offs,
    const int* __restrict__ csr, const float* __restrict__ dinv,
    const float* __restrict__ bconv, void* __restrict__ hout_, int N)
{
    const int wid = threadIdx.x >> 6;
    const int lane = threadIdx.x & 63;
    const int half = lane >> 5;
    const int l32 = lane & 31;
    const long node = (long)blockIdx.x * 4 + wid;
    if (node >= N) return;

    float4 acc = make_float4(0.f, 0.f, 0.f, 0.f);

    if (half == 0) {
        const uint2 v = *(const uint2*)&hws2[node * 64 + l32 * 2];
        const float2 a = __half22float2(__builtin_bit_cast(__half2, v.x));
        const float2 b = __half22float2(__builtin_bit_cast(__half2, v.y));
        acc.x = a.x; acc.y = a.y; acc.z = b.x; acc.w = b.y;
    }

    int k = offs[node];
    const int end = offs[node + 1];

    while (k + 8 <= end) {
        int s[4];
#pragma unroll
        for (int j = 0; j < 4; j++)
            s[j] = __builtin_nontemporal_load(&csr[k + 2 * j + half]);
        uint2 v[4];
#pragma unroll
        for (int j = 0; j < 4; j++)
            v[j] = *(const uint2*)&hws2[(long)s[j] * 64 + l32 * 2];

        // packed fp16 tree reduce: 4 rows -> 1 half2 pair
        const __half2 px = __hadd2(
            __hadd2(__builtin_bit_cast(__half2, v[0].x),
                    __builtin_bit_cast(__half2, v[1].x)),
            __hadd2(__builtin_bit_cast(__half2, v[2].x),
                    __builtin_bit_cast(__half2, v[3].x)));
        const __half2 py = __hadd2(
            __hadd2(__builtin_bit_cast(__half2, v[0].y),
                    __builtin_bit_cast(__half2, v[1].y)),
            __hadd2(__builtin_bit_cast(__half2, v[2].y),
                    __builtin_bit_cast(__half2, v[3].y)));
        const float2 fx = __half22float2(px);
        const float2 fy = __half22float2(py);
        acc.x += fx.x; acc.y += fx.y; acc.z += fy.x; acc.w += fy.y;
        k += 8;
    }
    while (k + 2 <= end) {
        const int s = __builtin_nontemporal_load(&csr[k + half]);
        const uint2 v = *(const uint2*)&hws2[(long)s * 64 + l32 * 2];
        const float2 a = __half22float2(__builtin_bit_cast(__half2, v.x));
        const float2 b = __half22float2(__builtin_bit_cast(__half2, v.y));
        acc.x += a.x; acc.y += a.y; acc.z += b.x; acc.w += b.y;
        k += 2;
    }
    if (k < end && half == 0) {
        const int s = csr[k];
        const uint2 v = *(const uint2*)&hws2[(long)s * 64 + l32 * 2];
        const float2 a = __half22float2(__builtin_bit_cast(__half2, v.x));
        const float2 b = __half22float2(__builtin_bit_cast(__half2, v.y));
        acc.x += a.x; acc.y += a.y; acc.z += b.x; acc.w += b.y;
    }

    acc.x += __shfl_xor(acc.x, 32);
    acc.y += __shfl_xor(acc.y, 32);
    acc.z += __shfl_xor(acc.z, 32);
    acc.w += __shfl_xor(acc.w, 32);

    if (half == 0) {
        const float di = dinv[node];
        const float4 b = *(const float4*)&bconv[l32 * 4];
        const float o0 = tanhf(acc.x * di + b.x);
        const float o1 = tanhf(acc.y * di + b.y);
        const float o2 = tanhf(acc.z * di + b.z);
        const float o3 = tanhf(acc.w * di + b.w);
        if constexpr (OUT_HALF) {
            __half* hout = (__half*)hout_;
            uint2 w;
            w.x = __builtin_bit_cast(unsigned, __floats2half2_rn(o0, o1));
            w.y = __builtin_bit_cast(unsigned, __floats2half2_rn(o2, o3));
            *(uint2*)&hout[node * 128 + l32 * 4] = w;
        } else {
            float* hout = (float*)hout_;
            *(float4*)&hout[node * 128 + l32 * 4] = make_float4(o0, o1, o2, o3);
        }
    }
}

// ---------------------------------------------------------------------------
// Graph ranges from sorted batch
// ---------------------------------------------------------------------------
__global__ void graph_bounds_k(const int* __restrict__ batch, int* __restrict__ goffs,
                               int N, int G)
{
    int i = blockIdx.x * 256 + threadIdx.x;
    if (i >= N) return;
    int b = batch[i];
    int prev = (i == 0) ? -1 : batch[i - 1];
    for (int g = prev + 1; g <= b; g++) goffs[g] = i;
    if (i == N - 1)
        for (int g = b + 1; g <= G; g++) goffs[g] = N;
}

// ---------------------------------------------------------------------------
// Pool stage 1: parallel partial reduction over node chunks.
// ---------------------------------------------------------------------------
__device__ __forceinline__ unsigned enc_f32(float x)
{
    unsigned u = __float_as_uint(x);
    return (u & 0x80000000u) ? ~u : (u | 0x80000000u);
}
__device__ __forceinline__ float dec_f32(unsigned u)
{
    return (u & 0x80000000u) ? __uint_as_float(u ^ 0x80000000u)
                             : __uint_as_float(~u);
}

#define POOL_CHUNK 32

__global__ __launch_bounds__(128) void pool_partial_k(
    const float* __restrict__ h, const int* __restrict__ batch,
    float* __restrict__ sums, unsigned* __restrict__ maxu, int N)
{
    const int t = threadIdx.x;
    const int lane = t & 31;
    const int sub = t >> 5;
    const int f4 = lane * 4;
    const int i0 = blockIdx.x * POOL_CHUNK;
    const int i1 = min(i0 + POOL_CHUNK, N);

    int cur = -1;
    float4 s = make_float4(0.f, 0.f, 0.f, 0.f);
    float4 m = make_float4(-INFINITY, -INFINITY, -INFINITY, -INFINITY);

#pragma unroll 4
    for (int i = i0 + sub; i < i1; i += 4) {
        const int b = batch[i];
        const float4 v = *(const float4*)&h[(long)i * 128 + f4];
        if (b != cur) {
            if (cur >= 0) {
                atomicAdd(&sums[cur * 128 + f4 + 0], s.x);
                atomicAdd(&sums[cur * 128 + f4 + 1], s.y);
                atomicAdd(&sums[cur * 128 + f4 + 2], s.z);
                atomicAdd(&sums[cur * 128 + f4 + 3], s.w);
                atomicMax(&maxu[cur * 128 + f4 + 0], enc_f32(m.x));
                atomicMax(&maxu[cur * 128 + f4 + 1], enc_f32(m.y));
                atomicMax(&maxu[cur * 128 + f4 + 2], enc_f32(m.z));
                atomicMax(&maxu[cur * 128 + f4 + 3], enc_f32(m.w));
            }
            s = make_float4(0.f, 0.f, 0.f, 0.f);
            m = make_float4(-INFINITY, -INFINITY, -INFINITY, -INFINITY);
            cur = b;
        }
        s.x += v.x; s.y += v.y; s.z += v.z; s.w += v.w;
        m.x = fmaxf(m.x, v.x); m.y = fmaxf(m.y, v.y);
        m.z = fmaxf(m.z, v.z); m.w = fmaxf(m.w, v.w);
    }
    if (cur >= 0) {
        atomicAdd(&sums[cur * 128 + f4 + 0], s.x);
        atomicAdd(&sums[cur * 128 + f4 + 1], s.y);
        atomicAdd(&sums[cur * 128 + f4 + 2], s.z);
        atomicAdd(&sums[cur * 128 + f4 + 3], s.w);
        atomicMax(&maxu[cur * 128 + f4 + 0], enc_f32(m.x));
        atomicMax(&maxu[cur * 128 + f4 + 1], enc_f32(m.y));
        atomicMax(&maxu[cur * 128 + f4 + 2], enc_f32(m.z));
        atomicMax(&maxu[cur * 128 + f4 + 3], enc_f32(m.w));
    }
}

// ---------------------------------------------------------------------------
// Pool stage 2: finalize [sum | max | mean] per graph
// ---------------------------------------------------------------------------
__global__ __launch_bounds__(128) void pool_final_k(
    const float* __restrict__ sums, const unsigned* __restrict__ maxu,
    const int* __restrict__ goffs, float* __restrict__ gout)
{
    const int g = blockIdx.x, f = threadIdx.x;
    const int cnt = goffs[g + 1] - goffs[g];
    const float s = sums[g * 128 + f];
    float mx = (cnt > 0) ? dec_f32(maxu[g * 128 + f]) : 0.0f;
    if (!isfinite(mx)) mx = 0.0f;
    const float mean = s / fmaxf((float)cnt, 1.0f);
    gout[g * 384 + f]       = s;
    gout[g * 384 + 128 + f] = mx;
    gout[g * 384 + 256 + f] = mean;
}

// ---------------------------------------------------------------------------
// MLP head: one block per graph
// ---------------------------------------------------------------------------
__global__ __launch_bounds__(192) void mlp_k(const float* __restrict__ gbuf,
                                             const float* __restrict__ W1,
                                             const float* __restrict__ b1,
                                             const float* __restrict__ W2,
                                             const float* __restrict__ b2,
                                             float* __restrict__ out)
{
    __shared__ float gr[384];
    __shared__ float g1[192];
    const int g = blockIdx.x, t = threadIdx.x;
    for (int i = t; i < 384; i += 192) gr[i] = gbuf[g * 384 + i];
    __syncthreads();
    float acc = b1[t];
    for (int k = 0; k < 384; k++) acc += gr[k] * W1[k * 192 + t];
    acc = acc > 0.f ? acc : 0.01f * acc;
    g1[t] = acc;
    __syncthreads();
    if (t < 10) {
        float a = b2[t];
        for (int k = 0; k < 192; k++) a += g1[k] * W2[k * 10 + t];
        a = a > 0.f ? a : 0.01f * a;
        out[g * 10 + t] = a;
    }
}

// ---------------------------------------------------------------------------
extern "C" void kernel_launch(void* const* d_in, const int* in_sizes, int n_in,
                              void* d_out, int out_size, void* d_ws, size_t ws_size,
                              hipStream_t stream)
{
    const float* x      = (const float*)d_in[0];
    const int*   ei     = (const int*)d_in[1];
    const int*   batch  = (const int*)d_in[2];
    const float* W_emb  = (const float*)d_in[3];
    const float* b_emb  = (const float*)d_in[4];
    const float* W_conv = (const float*)d_in[5];
    const float* b_conv = (const float*)d_in[6];
    const float* W1     = (const float*)d_in[7];
    const float* b1     = (const float*)d_in[8];
    const float* W2     = (const float*)d_in[9];
    const float* b2     = (const float*)d_in[10];
    float* out = (float*)d_out;

    const int N  = in_sizes[2];          // 100000
    const int E  = in_sizes[1] / 2;      // 1600000
    const int G  = 128;
    const int NL = 5;
    const int HID = 128;

    const int* e_src = ei;
    const int* e_dst = ei + E;

    // workspace carve-up
    char* ws = (char*)d_ws;
    size_t off = 0;
    auto alloc = [&](size_t bytes) -> void* {
        void* p = ws + off;
        off += (bytes + 255) & ~(size_t)255;
        return p;
    };
    float*    hbuf     = (float*)   alloc((size_t)N * HID * 4);  // final fp32 h
    __half*   hh       = (__half*)  alloc((size_t)N * HID * 2);  // fp16 h
    __half*   hws      = (__half*)  alloc((size_t)N * HID * 2);  // fp16 h@W*dinv
    __half*   wt16     = (__half*)  alloc((size_t)NL * HID * HID * 2);
    __half*   wt16e    = (__half*)  alloc((size_t)64 * HID * 2);
    float*    dinv     = (float*)   alloc((size_t)N * 4);
    int*      cnt      = (int*)     alloc((size_t)N * 4);
    int*      offs     = (int*)     alloc((size_t)(N + 1) * 4);
    int*      bsums    = (int*)     alloc(512 * 4);
    int*      csr      = (int*)     alloc((size_t)E * 4);
    int*      rank     = (int*)     alloc((size_t)E * 4);
    int*      goffs    = (int*)     alloc((size_t)(G + 1) * 4);
    float*    gbuf     = (float*)   alloc((size_t)G * 384 * 4);
    float*    psums    = (float*)   alloc((size_t)G * 128 * 4);
    unsigned* pmaxu    = (unsigned*)alloc((size_t)G * 128 * 4);

    const int nb_nodes = (N + 255) / 256;
    const int nb_edges = (E + 255) / 256;

    // 0) convert weights -> fp16 transposed [l][n][k]
    const int wtot = NL * HID * HID;
    convert_w_k<128><<<(wtot + 255) / 256, 256, 0, stream>>>(W_conv, wt16, wtot);
    convert_w_k<64><<<(64 * HID + 255) / 256, 256, 0, stream>>>(W_emb, wt16e,
                                                                64 * HID);

    // 1) degree + rank
    (void)hipMemsetAsync(cnt, 0, (size_t)N * 4, stream);
    count_edges_k<<<nb_edges, 256, 0, stream>>>(e_dst, cnt, rank, E);

    // 2) CSR offsets (+ dinv fused into block scan)
    scan_block_k<<<nb_nodes, 256, 0, stream>>>(cnt, offs, bsums, dinv, N);
    scan_tops_k<<<1, 512, 0, stream>>>(bsums, nb_nodes);
    scan_add_k<<<nb_nodes, 256, 0, stream>>>(offs, bsums, N, E);

    // 3) CSR fill (atomic-free)
    fill_csr_k<<<nb_edges, 256, 0, stream>>>(e_src, e_dst, offs, rank, csr, E);

    // 4) embedding (MFMA): hh = fp16(x @ W_emb + b_emb)
    dense_mfma_k<64, true, false, false><<<(N + 63) / 64, 256, 0, stream>>>(
        x, wt16e, b_emb, nullptr, hh, N);

    // 5) GCN layers: dense hh->hws (fp16, *dinv); agg hws->hh (or fp32 last)
    for (int l = 0; l < NL; l++) {
        dense_mfma_k<128, false, true, true><<<(N + 63) / 64, 256, 0, stream>>>(
            hh, wt16 + (size_t)l * HID * HID, nullptr, dinv, hws, N);
        if (l < NL - 1) {
            aggregate_k<true><<<(N + 3) / 4, 256, 0, stream>>>(
                (const __half2*)hws, offs, csr, dinv,
                b_conv + (size_t)l * HID, hh, N);
        } else {
            aggregate_k<false><<<(N + 3) / 4, 256, 0, stream>>>(
                (const __half2*)hws, offs, csr, dinv,
                b_conv + (size_t)l * HID, hbuf, N);
        }
    }

    // 6) pooling (parallel two-stage)
    graph_bounds_k<<<nb_nodes, 256, 0, stream>>>(batch, goffs, N, G);
    (void)hipMemsetAsync(psums, 0, (size_t)G * 128 * 4, stream);
    (void)hipMemsetAsync(pmaxu, 0, (size_t)G * 128 * 4, stream);
    pool_partial_k<<<(N + POOL_CHUNK - 1) / POOL_CHUNK, 128, 0, stream>>>(
        hbuf, batch, psums, pmaxu, N);
    pool_final_k<<<G, 128, 0, stream>>>(psums, pmaxu, goffs, gbuf);

    // 7) MLP head
    mlp_k<<<G, 192, 0, stream>>>(gbuf, W1, b1, W2, b2, out);
}

// Round 15
// 648.130 us; speedup vs baseline: 1.0888x; 1.0888x over previous
//
#include <hip/hip_runtime.h>
#include <hip/hip_fp16.h>
#include <math.h>

typedef _Float16 f16x4 __attribute__((ext_vector_type(4)));
typedef float    f32x4 __attribute__((ext_vector_type(4)));

// ---------------------------------------------------------------------------
// W_conv fp32 [L][k][n] (n=128) -> fp16 transposed Wt [L][n][k]
// ---------------------------------------------------------------------------
__global__ void convert_w_k(const float* __restrict__ W, __half* __restrict__ Wt,
                            int total)
{
    int i = blockIdx.x * 256 + threadIdx.x;
    if (i >= total) return;
    const int nk = 128 * 128;
    const int l = i / nk;
    const int rem = i % nk;
    const int n = rem / 128;
    const int k = rem % 128;
    Wt[i] = __float2half(W[(size_t)l * nk + k * 128 + n]);
}

// ---------------------------------------------------------------------------
// Fuse embedding into layer-0: Wf_t[n][k64] = sum_j W_emb[k][j] W0[j][n],
// bf[n] = sum_j b_emb[j] W0[j][n].  (fp32 math, fp16-T output)
// 64*128 = 8192 outputs, one thread each.
// ---------------------------------------------------------------------------
__global__ void fuse_w_k(const float* __restrict__ W_emb,   // [64][128]
                         const float* __restrict__ b_emb,   // [128]
                         const float* __restrict__ W0,      // [128][128]
                         __half* __restrict__ Wf_t,         // [128][64] (n,k)
                         float* __restrict__ bf)            // [128]
{
    int i = blockIdx.x * 256 + threadIdx.x;
    if (i >= 64 * 128) return;
    const int n = i >> 6;          // 0..127
    const int k = i & 63;          // 0..63
    float s = 0.f;
    for (int j = 0; j < 128; j++)
        s += W_emb[k * 128 + j] * W0[j * 128 + n];
    Wf_t[n * 64 + k] = __float2half(s);
    if (k == 0) {
        float sb = 0.f;
        for (int j = 0; j < 128; j++)
            sb += b_emb[j] * W0[j * 128 + n];
        bf[n] = sb;
    }
}

// ---------------------------------------------------------------------------
// MFMA dense: out[M,128] = A[M,K] @ W(fp16) [+bias] [*rowscale], out fp16.
// IN_HALF: A is fp16 (loaded raw); else fp32 (converted during staging).
// Epilogue: out = (acc + bias) * rowscale.
// ---------------------------------------------------------------------------
template<int K, bool HAS_BIAS, bool IN_HALF, bool SCALE>
__global__ __launch_bounds__(256) void dense_mfma_k(
    const void* __restrict__ A_, const __half* __restrict__ Wt,
    const float* __restrict__ bias, const float* __restrict__ rowscale,
    __half* __restrict__ out, int M)
{
    constexpr int KP = K + 8;
    __shared__ _Float16 Ah[64 * KP];
    __shared__ _Float16 Wl[128 * KP];

    const int t = threadIdx.x;
    const long row0 = (long)blockIdx.x * 64;

    for (int i = t; i < K * 16; i += 256) {
        const int n = i / (K / 8);
        const int kq = i % (K / 8);
        *(float4*)&Wl[n * KP + kq * 8] = *(const float4*)&Wt[n * K + kq * 8];
    }
    if constexpr (IN_HALF) {
        const __half* A = (const __half*)A_;
        for (int i = t; i < K * 8; i += 256) {
            const int r = i / (K / 8);
            const int kq = i % (K / 8);
            long gr = row0 + r; if (gr > (long)M - 1) gr = (long)M - 1;
            *(float4*)&Ah[r * KP + kq * 8] = *(const float4*)&A[gr * K + kq * 8];
        }
    } else {
        const float* A = (const float*)A_;
        for (int i = t; i < K * 16; i += 256) {
            const int r = i / (K / 4);
            const int kq = i % (K / 4);
            long gr = row0 + r; if (gr > (long)M - 1) gr = (long)M - 1;
            const float4 v = *(const float4*)&A[gr * K + kq * 4];
            f16x4 h4 = { (_Float16)v.x, (_Float16)v.y, (_Float16)v.z, (_Float16)v.w };
            *(f16x4*)&Ah[r * KP + kq * 4] = h4;
        }
    }
    __syncthreads();

    const int wid = t >> 6;
    const int lane = t & 63;
    const int lrow = lane & 15;
    const int lk = (lane >> 4) * 4;

    f32x4 acc[8];
#pragma unroll
    for (int c = 0; c < 8; c++) acc[c] = f32x4{0.f, 0.f, 0.f, 0.f};

#pragma unroll
    for (int kc = 0; kc < K / 16; kc++) {
        const int kbase = kc * 16 + lk;
        const f16x4 a = *(const f16x4*)&Ah[(wid * 16 + lrow) * KP + kbase];
#pragma unroll
        for (int c = 0; c < 8; c++) {
            const f16x4 b = *(const f16x4*)&Wl[(c * 16 + lrow) * KP + kbase];
            acc[c] = __builtin_amdgcn_mfma_f32_16x16x16f16(a, b, acc[c], 0, 0, 0);
        }
    }

    const int orow = wid * 16 + (lane >> 4) * 4;
#pragma unroll
    for (int r = 0; r < 4; r++) {
        const long grow = row0 + orow + r;
        if (grow < M) {
            const float sc = SCALE ? rowscale[grow] : 1.0f;
#pragma unroll
            for (int c = 0; c < 8; c++) {
                float v = acc[c][r];
                if (HAS_BIAS) v += bias[c * 16 + lrow];
                out[grow * 128 + c * 16 + lrow] = __float2half(v * sc);
            }
        }
    }
}

// ---------------------------------------------------------------------------
// Degree count + rank capture
// ---------------------------------------------------------------------------
__global__ void count_edges_k(const int* __restrict__ dst, int* __restrict__ cnt,
                              int* __restrict__ rank, int E)
{
    int e = blockIdx.x * 256 + threadIdx.x;
    if (e < E) rank[e] = atomicAdd(&cnt[dst[e]], 1);
}

// ---------------------------------------------------------------------------
// Block scan (+ dinv computed here)
// ---------------------------------------------------------------------------
__global__ void scan_block_k(const int* __restrict__ cnt, int* __restrict__ offs,
                             int* __restrict__ bsums, float* __restrict__ dinv, int N)
{
    __shared__ int tmp[256];
    int i = blockIdx.x * 256 + threadIdx.x;
    int v = (i < N) ? cnt[i] : 0;
    if (i < N) dinv[i] = rsqrtf((float)v + 1.0f);   // +1 = self loop
    tmp[threadIdx.x] = v;
    __syncthreads();
    for (int off = 1; off < 256; off <<= 1) {
        int add = (threadIdx.x >= off) ? tmp[threadIdx.x - off] : 0;
        __syncthreads();
        tmp[threadIdx.x] += add;
        __syncthreads();
    }
    if (i < N) offs[i] = tmp[threadIdx.x] - v;
    if (threadIdx.x == 255) bsums[blockIdx.x] = tmp[255];
}

__global__ void scan_tops_k(int* __restrict__ bsums, int nb)
{
    __shared__ int tmp[512];
    int t = threadIdx.x;
    int v = (t < nb) ? bsums[t] : 0;
    tmp[t] = v;
    __syncthreads();
    for (int off = 1; off < 512; off <<= 1) {
        int add = (t >= off) ? tmp[t - off] : 0;
        __syncthreads();
        tmp[t] += add;
        __syncthreads();
    }
    if (t < nb) bsums[t] = tmp[t] - v;
}

__global__ void scan_add_k(int* __restrict__ offs, const int* __restrict__ bsums,
                           int N, int E)
{
    int i = blockIdx.x * 256 + threadIdx.x;
    if (i < N) offs[i] += bsums[blockIdx.x];
    if (i == 0) offs[N] = E;
}

// ---------------------------------------------------------------------------
// CSR fill: slot = offs[dst] + rank (atomic-free)
// ---------------------------------------------------------------------------
__global__ void fill_csr_k(const int* __restrict__ src, const int* __restrict__ dst,
                           const int* __restrict__ offs, const int* __restrict__ rank,
                           int* __restrict__ csr, int E)
{
    int e = blockIdx.x * 256 + threadIdx.x;
    if (e >= E) return;
    csr[offs[dst[e]] + rank[e]] = src[e];
}

// ---------------------------------------------------------------------------
// Aggregation v3 (proven 74 us): half-wave, 2 edges/VMEM, 4 gathers in
// flight, plain L2-cached csr loads, fp32 accumulate.
// ---------------------------------------------------------------------------
template<bool OUT_HALF>
__global__ __launch_bounds__(256) void aggregate_k(
    const __half2* __restrict__ hws2, const int* __restrict__ offs,
    const int* __restrict__ csr, const float* __restrict__ dinv,
    const float* __restrict__ bconv, void* __restrict__ hout_, int N)
{
    const int wid = threadIdx.x >> 6;
    const int lane = threadIdx.x & 63;
    const int half = lane >> 5;
    const int l32 = lane & 31;
    const long node = (long)blockIdx.x * 4 + wid;
    if (node >= N) return;

    float4 acc = make_float4(0.f, 0.f, 0.f, 0.f);

    if (half == 0) {
        const uint2 v = *(const uint2*)&hws2[node * 64 + l32 * 2];
        const float2 a = __half22float2(__builtin_bit_cast(__half2, v.x));
        const float2 b = __half22float2(__builtin_bit_cast(__half2, v.y));
        acc.x = a.x; acc.y = a.y; acc.z = b.x; acc.w = b.y;
    }

    int k = offs[node];
    const int end = offs[node + 1];

    while (k + 8 <= end) {
        int s[4];
#pragma unroll
        for (int j = 0; j < 4; j++) s[j] = csr[k + 2 * j + half];
        uint2 v[4];
#pragma unroll
        for (int j = 0; j < 4; j++)
            v[j] = *(const uint2*)&hws2[(long)s[j] * 64 + l32 * 2];
#pragma unroll
        for (int j = 0; j < 4; j++) {
            const float2 a = __half22float2(__builtin_bit_cast(__half2, v[j].x));
            const float2 b = __half22float2(__builtin_bit_cast(__half2, v[j].y));
            acc.x += a.x; acc.y += a.y; acc.z += b.x; acc.w += b.y;
        }
        k += 8;
    }
    while (k + 2 <= end) {
        const int s = csr[k + half];
        const uint2 v = *(const uint2*)&hws2[(long)s * 64 + l32 * 2];
        const float2 a = __half22float2(__builtin_bit_cast(__half2, v.x));
        const float2 b = __half22float2(__builtin_bit_cast(__half2, v.y));
        acc.x += a.x; acc.y += a.y; acc.z += b.x; acc.w += b.y;
        k += 2;
    }
    if (k < end && half == 0) {
        const int s = csr[k];
        const uint2 v = *(const uint2*)&hws2[(long)s * 64 + l32 * 2];
        const float2 a = __half22float2(__builtin_bit_cast(__half2, v.x));
        const float2 b = __half22float2(__builtin_bit_cast(__half2, v.y));
        acc.x += a.x; acc.y += a.y; acc.z += b.x; acc.w += b.y;
    }

    acc.x += __shfl_xor(acc.x, 32);
    acc.y += __shfl_xor(acc.y, 32);
    acc.z += __shfl_xor(acc.z, 32);
    acc.w += __shfl_xor(acc.w, 32);

    if (half == 0) {
        const float di = dinv[node];
        const float4 b = *(const float4*)&bconv[l32 * 4];
        const float o0 = tanhf(acc.x * di + b.x);
        const float o1 = tanhf(acc.y * di + b.y);
        const float o2 = tanhf(acc.z * di + b.z);
        const float o3 = tanhf(acc.w * di + b.w);
        if constexpr (OUT_HALF) {
            __half* hout = (__half*)hout_;
            uint2 w;
            w.x = __builtin_bit_cast(unsigned, __floats2half2_rn(o0, o1));
            w.y = __builtin_bit_cast(unsigned, __floats2half2_rn(o2, o3));
            *(uint2*)&hout[node * 128 + l32 * 4] = w;
        } else {
            float* hout = (float*)hout_;
            *(float4*)&hout[node * 128 + l32 * 4] = make_float4(o0, o1, o2, o3);
        }
    }
}

// ---------------------------------------------------------------------------
// Graph ranges from sorted batch
// ---------------------------------------------------------------------------
__global__ void graph_bounds_k(const int* __restrict__ batch, int* __restrict__ goffs,
                               int N, int G)
{
    int i = blockIdx.x * 256 + threadIdx.x;
    if (i >= N) return;
    int b = batch[i];
    int prev = (i == 0) ? -1 : batch[i - 1];
    for (int g = prev + 1; g <= b; g++) goffs[g] = i;
    if (i == N - 1)
        for (int g = b + 1; g <= G; g++) goffs[g] = N;
}

// ---------------------------------------------------------------------------
// Pool stage 1: parallel partial reduction over node chunks.
// ---------------------------------------------------------------------------
__device__ __forceinline__ unsigned enc_f32(float x)
{
    unsigned u = __float_as_uint(x);
    return (u & 0x80000000u) ? ~u : (u | 0x80000000u);
}
__device__ __forceinline__ float dec_f32(unsigned u)
{
    return (u & 0x80000000u) ? __uint_as_float(u ^ 0x80000000u)
                             : __uint_as_float(~u);
}

#define POOL_CHUNK 32

__global__ __launch_bounds__(128) void pool_partial_k(
    const float* __restrict__ h, const int* __restrict__ batch,
    float* __restrict__ sums, unsigned* __restrict__ maxu, int N)
{
    const int t = threadIdx.x;
    const int lane = t & 31;
    const int sub = t >> 5;
    const int f4 = lane * 4;
    const int i0 = blockIdx.x * POOL_CHUNK;
    const int i1 = min(i0 + POOL_CHUNK, N);

    int cur = -1;
    float4 s = make_float4(0.f, 0.f, 0.f, 0.f);
    float4 m = make_float4(-INFINITY, -INFINITY, -INFINITY, -INFINITY);

#pragma unroll 4
    for (int i = i0 + sub; i < i1; i += 4) {
        const int b = batch[i];
        const float4 v = *(const float4*)&h[(long)i * 128 + f4];
        if (b != cur) {
            if (cur >= 0) {
                atomicAdd(&sums[cur * 128 + f4 + 0], s.x);
                atomicAdd(&sums[cur * 128 + f4 + 1], s.y);
                atomicAdd(&sums[cur * 128 + f4 + 2], s.z);
                atomicAdd(&sums[cur * 128 + f4 + 3], s.w);
                atomicMax(&maxu[cur * 128 + f4 + 0], enc_f32(m.x));
                atomicMax(&maxu[cur * 128 + f4 + 1], enc_f32(m.y));
                atomicMax(&maxu[cur * 128 + f4 + 2], enc_f32(m.z));
                atomicMax(&maxu[cur * 128 + f4 + 3], enc_f32(m.w));
            }
            s = make_float4(0.f, 0.f, 0.f, 0.f);
            m = make_float4(-INFINITY, -INFINITY, -INFINITY, -INFINITY);
            cur = b;
        }
        s.x += v.x; s.y += v.y; s.z += v.z; s.w += v.w;
        m.x = fmaxf(m.x, v.x); m.y = fmaxf(m.y, v.y);
        m.z = fmaxf(m.z, v.z); m.w = fmaxf(m.w, v.w);
    }
    if (cur >= 0) {
        atomicAdd(&sums[cur * 128 + f4 + 0], s.x);
        atomicAdd(&sums[cur * 128 + f4 + 1], s.y);
        atomicAdd(&sums[cur * 128 + f4 + 2], s.z);
        atomicAdd(&sums[cur * 128 + f4 + 3], s.w);
        atomicMax(&maxu[cur * 128 + f4 + 0], enc_f32(m.x));
        atomicMax(&maxu[cur * 128 + f4 + 1], enc_f32(m.y));
        atomicMax(&maxu[cur * 128 + f4 + 2], enc_f32(m.z));
        atomicMax(&maxu[cur * 128 + f4 + 3], enc_f32(m.w));
    }
}

// ---------------------------------------------------------------------------
// Pool stage 2: finalize [sum | max | mean] per graph
// ---------------------------------------------------------------------------
__global__ __launch_bounds__(128) void pool_final_k(
    const float* __restrict__ sums, const unsigned* __restrict__ maxu,
    const int* __restrict__ goffs, float* __restrict__ gout)
{
    const int g = blockIdx.x, f = threadIdx.x;
    const int cnt = goffs[g + 1] - goffs[g];
    const float s = sums[g * 128 + f];
    float mx = (cnt > 0) ? dec_f32(maxu[g * 128 + f]) : 0.0f;
    if (!isfinite(mx)) mx = 0.0f;
    const float mean = s / fmaxf((float)cnt, 1.0f);
    gout[g * 384 + f]       = s;
    gout[g * 384 + 128 + f] = mx;
    gout[g * 384 + 256 + f] = mean;
}

// ---------------------------------------------------------------------------
// MLP head: one block per graph
// ---------------------------------------------------------------------------
__global__ __launch_bounds__(192) void mlp_k(const float* __restrict__ gbuf,
                                             const float* __restrict__ W1,
                                             const float* __restrict__ b1,
                                             const float* __restrict__ W2,
                                             const float* __restrict__ b2,
                                             float* __restrict__ out)
{
    __shared__ float gr[384];
    __shared__ float g1[192];
    const int g = blockIdx.x, t = threadIdx.x;
    for (int i = t; i < 384; i += 192) gr[i] = gbuf[g * 384 + i];
    __syncthreads();
    float acc = b1[t];
    for (int k = 0; k < 384; k++) acc += gr[k] * W1[k * 192 + t];
    acc = acc > 0.f ? acc : 0.01f * acc;
    g1[t] = acc;
    __syncthreads();
    if (t < 10) {
        float a = b2[t];
        for (int k = 0; k < 192; k++) a += g1[k] * W2[k * 10 + t];
        a = a > 0.f ? a : 0.01f * a;
        out[g * 10 + t] = a;
    }
}

// ---------------------------------------------------------------------------
extern "C" void kernel_launch(void* const* d_in, const int* in_sizes, int n_in,
                              void* d_out, int out_size, void* d_ws, size_t ws_size,
                              hipStream_t stream)
{
    const float* x      = (const float*)d_in[0];
    const int*   ei     = (const int*)d_in[1];
    const int*   batch  = (const int*)d_in[2];
    const float* W_emb  = (const float*)d_in[3];
    const float* b_emb  = (const float*)d_in[4];
    const float* W_conv = (const float*)d_in[5];
    const float* b_conv = (const float*)d_in[6];
    const float* W1     = (const float*)d_in[7];
    const float* b1     = (const float*)d_in[8];
    const float* W2     = (const float*)d_in[9];
    const float* b2     = (const float*)d_in[10];
    float* out = (float*)d_out;

    const int N  = in_sizes[2];          // 100000
    const int E  = in_sizes[1] / 2;      // 1600000
    const int G  = 128;
    const int NL = 5;
    const int HID = 128;

    const int* e_src = ei;
    const int* e_dst = ei + E;

    // workspace carve-up
    char* ws = (char*)d_ws;
    size_t off = 0;
    auto alloc = [&](size_t bytes) -> void* {
        void* p = ws + off;
        off += (bytes + 255) & ~(size_t)255;
        return p;
    };
    float*    hbuf     = (float*)   alloc((size_t)N * HID * 4);  // final fp32 h
    __half*   hh       = (__half*)  alloc((size_t)N * HID * 2);  // fp16 h
    __half*   hws      = (__half*)  alloc((size_t)N * HID * 2);  // fp16 h@W*dinv
    __half*   wt16     = (__half*)  alloc((size_t)NL * HID * HID * 2);
    __half*   wtf      = (__half*)  alloc((size_t)HID * 64 * 2); // fused emb+W0
    float*    bf       = (float*)   alloc((size_t)HID * 4);
    float*    dinv     = (float*)   alloc((size_t)N * 4);
    int*      cnt      = (int*)     alloc((size_t)N * 4);
    int*      offs     = (int*)     alloc((size_t)(N + 1) * 4);
    int*      bsums    = (int*)     alloc(512 * 4);
    int*      csr      = (int*)     alloc((size_t)E * 4);
    int*      rank     = (int*)     alloc((size_t)E * 4);
    int*      goffs    = (int*)     alloc((size_t)(G + 1) * 4);
    float*    gbuf     = (float*)   alloc((size_t)G * 384 * 4);
    float*    psums    = (float*)   alloc((size_t)G * 128 * 4);
    unsigned* pmaxu    = (unsigned*)alloc((size_t)G * 128 * 4);

    const int nb_nodes = (N + 255) / 256;
    const int nb_edges = (E + 255) / 256;

    // 0) weight prep: W_conv -> fp16-T; fused (W_emb@W0, b_emb@W0)
    const int wtot = NL * HID * HID;
    convert_w_k<<<(wtot + 255) / 256, 256, 0, stream>>>(W_conv, wt16, wtot);
    fuse_w_k<<<(64 * HID + 255) / 256, 256, 0, stream>>>(W_emb, b_emb, W_conv,
                                                         wtf, bf);

    // 1) degree + rank
    (void)hipMemsetAsync(cnt, 0, (size_t)N * 4, stream);
    count_edges_k<<<nb_edges, 256, 0, stream>>>(e_dst, cnt, rank, E);

    // 2) CSR offsets (+ dinv fused into block scan)
    scan_block_k<<<nb_nodes, 256, 0, stream>>>(cnt, offs, bsums, dinv, N);
    scan_tops_k<<<1, 512, 0, stream>>>(bsums, nb_nodes);
    scan_add_k<<<nb_nodes, 256, 0, stream>>>(offs, bsums, N, E);

    // 3) CSR fill (atomic-free)
    fill_csr_k<<<nb_edges, 256, 0, stream>>>(e_src, e_dst, offs, rank, csr, E);

    // 4) layer-0 dense fused with embedding:
    //    hws0 = (x @ Wfused + bfused) * dinv   (x fp32, K=64)
    dense_mfma_k<64, true, false, true><<<(N + 63) / 64, 256, 0, stream>>>(
        x, wtf, bf, dinv, hws, N);

    // 5) GCN layers
    for (int l = 0; l < NL; l++) {
        if (l > 0) {
            dense_mfma_k<128, false, true, true><<<(N + 63) / 64, 256, 0, stream>>>(
                hh, wt16 + (size_t)l * HID * HID, nullptr, dinv, hws, N);
        }
        if (l < NL - 1) {
            aggregate_k<true><<<(N + 3) / 4, 256, 0, stream>>>(
                (const __half2*)hws, offs, csr, dinv,
                b_conv + (size_t)l * HID, hh, N);
        } else {
            aggregate_k<false><<<(N + 3) / 4, 256, 0, stream>>>(
                (const __half2*)hws, offs, csr, dinv,
                b_conv + (size_t)l * HID, hbuf, N);
        }
    }

    // 6) pooling (parallel two-stage)
    graph_bounds_k<<<nb_nodes, 256, 0, stream>>>(batch, goffs, N, G);
    (void)hipMemsetAsync(psums, 0, (size_t)G * 128 * 4, stream);
    (void)hipMemsetAsync(pmaxu, 0, (size_t)G * 128 * 4, stream);
    pool_partial_k<<<(N + POOL_CHUNK - 1) / POOL_CHUNK, 128, 0, stream>>>(
        hbuf, batch, psums, pmaxu, N);
    pool_final_k<<<G, 128, 0, stream>>>(psums, pmaxu, goffs, gbuf);

    // 7) MLP head
    mlp_k<<<G, 192, 0, stream>>>(gbuf, W1, b1, W2, b2, out);
}